// Round 9
// baseline (163.650 us; speedup 1.0000x reference)
//
#include <hip/hip_runtime.h>
#include <math.h>

#define NN 10000
#define FIN 512
#define HD 40
#define GEPS 1e-5f

#define ZI4 ((2 * NN + 2 * HD) / 4)       // 5020 int4s (cnt, cur, stats)
#define MM1_BLOCKS ((NN + 15) / 16)       // 625
#define ZERO_BLOCKS ((ZI4 + 255) / 256)   // 20

// ---------------- CSR build ----------------
__global__ void k_hist(const int* __restrict__ dst, int* __restrict__ cnt, int E) {
    int e = blockIdx.x * blockDim.x + threadIdx.x;
    if (e < E) atomicAdd(&cnt[dst[e]], 1);
}

// single block, 1024 threads; 10 rows per thread; fused dis=rsqrt(deg)
__global__ __launch_bounds__(1024) void k_scan(const int* __restrict__ cnt,
                                               int* __restrict__ rowstart,
                                               float* __restrict__ dis) {
    __shared__ int lds[1024];
    const int t = threadIdx.x;
    const int start = t * 10;
    const int end = min(start + 10, NN);
    int s = 0;
    for (int i = start; i < end; ++i) s += cnt[i];
    lds[t] = s;
    __syncthreads();
    for (int off = 1; off < 1024; off <<= 1) {
        int v = (t >= off) ? lds[t - off] : 0;
        __syncthreads();
        lds[t] += v;
        __syncthreads();
    }
    int run = lds[t] - s;   // exclusive prefix
    for (int i = start; i < end; ++i) {
        int c = cnt[i];
        rowstart[i] = run;
        run += c;
        dis[i] = rsqrtf((float)c);
    }
    if (end == NN) rowstart[NN] = run;
}

__global__ void k_fill(const int* __restrict__ src, const int* __restrict__ dst,
                       const int* __restrict__ rowstart, int* __restrict__ cur,
                       const float* __restrict__ dis, int2* __restrict__ csr, int E) {
    int e = blockIdx.x * blockDim.x + threadIdx.x;
    if (e >= E) return;
    int s = src[e], d = dst[e];
    int pos = rowstart[d] + atomicAdd(&cur[d], 1);
    int2 v;
    v.x = s;
    v.y = __float_as_int(dis[s] * dis[d]);
    csr[pos] = v;
}

// ---------------- h1 = x @ W1 (16 rows x 16 kgroups; spare blocks zero cnt/cur/stats) ----------------
__global__ __launch_bounds__(256) void k_mm1z(const float* __restrict__ x,
                                              const float* __restrict__ W1,
                                              float* __restrict__ h1,
                                              int4* __restrict__ zbuf) {
    if (blockIdx.x >= MM1_BLOCKS) {       // zero-duty blocks
        int i = (blockIdx.x - MM1_BLOCKS) * 256 + threadIdx.x;
        if (i < ZI4) zbuf[i] = make_int4(0, 0, 0, 0);
        return;
    }
    __shared__ float red[256 * 41];       // 41-pad: odd stride -> conflict-free
    const int tid = threadIdx.x;
    const int r = tid & 15;
    const int kg = tid >> 4;              // 0..15, 32 k each
    const int row = blockIdx.x * 16 + r;
    const int rowc = min(row, NN - 1);
    const float4* xr = (const float4*)(x + (size_t)rowc * FIN + kg * 32);
    float acc[HD];
#pragma unroll
    for (int c = 0; c < HD; ++c) acc[c] = 0.f;
#pragma unroll 2
    for (int q = 0; q < 8; ++q) {
        float4 xv = xr[q];
        const float* wbase = W1 + (size_t)(kg * 32 + q * 4) * HD;
#pragma unroll
        for (int kk = 0; kk < 4; ++kk) {
            float xs = (kk == 0) ? xv.x : (kk == 1) ? xv.y : (kk == 2) ? xv.z : xv.w;
#pragma unroll
            for (int c4 = 0; c4 < 10; ++c4) {
                float4 wv = *(const float4*)(wbase + kk * HD + c4 * 4);
                acc[c4 * 4 + 0] = fmaf(xs, wv.x, acc[c4 * 4 + 0]);
                acc[c4 * 4 + 1] = fmaf(xs, wv.y, acc[c4 * 4 + 1]);
                acc[c4 * 4 + 2] = fmaf(xs, wv.z, acc[c4 * 4 + 2]);
                acc[c4 * 4 + 3] = fmaf(xs, wv.w, acc[c4 * 4 + 3]);
            }
        }
    }
#pragma unroll
    for (int c = 0; c < HD; ++c) red[tid * 41 + c] = acc[c];
    __syncthreads();
    if (tid < 160) {                      // 16 rows x 10 float4
        int rr = tid / 10, c4 = tid % 10;
        float o0 = 0.f, o1 = 0.f, o2 = 0.f, o3 = 0.f;
#pragma unroll
        for (int kg2 = 0; kg2 < 16; ++kg2) {
            const float* p = &red[(kg2 * 16 + rr) * 41 + c4 * 4];
            o0 += p[0]; o1 += p[1]; o2 += p[2]; o3 += p[3];
        }
        int orow = blockIdx.x * 16 + rr;
        if (orow < NN)
            *(float4*)&h1[(size_t)orow * HD + c4 * 4] = make_float4(o0, o1, o2, o3);
    }
}

// ---------------- gather1: agg1 = A_hat @ h1 ; fused GraphNorm stats ----------------
// 4 threads per (node,c4) slot; csr software prefetch; LDS combine.
__global__ __launch_bounds__(256) void k_gather1(const int* __restrict__ rowstart,
                                                 const int2* __restrict__ csr,
                                                 const float* __restrict__ hin,
                                                 const float* __restrict__ b1,
                                                 float* __restrict__ agg1,
                                                 float* __restrict__ stats) {
    __shared__ float4 part[256];
    __shared__ float s0[HD], s1[HD];
    const int t = threadIdx.x;
    if (t < HD) { s0[t] = 0.f; s1[t] = 0.f; }
    const int slot = blockIdx.x * 64 + (t & 63);
    const int quarter = t >> 6;
    const int c4 = slot % 10;
    float4 acc = make_float4(0.f, 0.f, 0.f, 0.f);
    if (slot < NN * 10) {
        int n = slot / 10;
        int j1 = rowstart[n + 1];
        int j = rowstart[n] + quarter;
        if (j < j1) {
            int2 se = csr[j];
            while (true) {
                int jn = j + 4;
                int2 sen;
                if (jn < j1) sen = csr[jn];
                float cf = __int_as_float(se.y);
                float4 v = *(const float4*)&hin[(size_t)se.x * HD + c4 * 4];
                acc.x = fmaf(v.x, cf, acc.x);
                acc.y = fmaf(v.y, cf, acc.y);
                acc.z = fmaf(v.z, cf, acc.z);
                acc.w = fmaf(v.w, cf, acc.w);
                if (jn >= j1) break;
                se = sen; j = jn;
            }
        }
    }
    part[t] = acc;
    __syncthreads();
    if (quarter == 0 && slot < NN * 10) {
        float4 p1 = part[t + 64], p2 = part[t + 128], p3 = part[t + 192];
        acc.x += p1.x + p2.x + p3.x;
        acc.y += p1.y + p2.y + p3.y;
        acc.z += p1.z + p2.z + p3.z;
        acc.w += p1.w + p2.w + p3.w;
        ((float4*)agg1)[slot] = acc;
        float4 bv = ((const float4*)b1)[c4];
        float vx = acc.x + bv.x, vy = acc.y + bv.y, vz = acc.z + bv.z, vw = acc.w + bv.w;
        atomicAdd(&s0[c4 * 4 + 0], vx); atomicAdd(&s0[c4 * 4 + 1], vy);
        atomicAdd(&s0[c4 * 4 + 2], vz); atomicAdd(&s0[c4 * 4 + 3], vw);
        atomicAdd(&s1[c4 * 4 + 0], vx * vx); atomicAdd(&s1[c4 * 4 + 1], vy * vy);
        atomicAdd(&s1[c4 * 4 + 2], vz * vz); atomicAdd(&s1[c4 * 4 + 3], vw * vw);
    }
    __syncthreads();
    if (t < HD) {
        atomicAdd(&stats[t], s0[t]);
        atomicAdd(&stats[HD + t], s1[t]);
    }
}

// ---------------- gather2: colsc prologue + fused norm+relu+aggregate ----------------
__global__ __launch_bounds__(256) void k_gather2(const int* __restrict__ rowstart,
                                                 const int2* __restrict__ csr,
                                                 const float* __restrict__ agg1,
                                                 const float* __restrict__ stats,
                                                 const float* __restrict__ b1,
                                                 const float* __restrict__ gw,
                                                 const float* __restrict__ gb,
                                                 const float* __restrict__ ga,
                                                 float* __restrict__ aggh) {
    __shared__ float4 part[256];
    __shared__ float csc[2 * HD];
    const int t = threadIdx.x;
    if (t < HD) {
        float m   = stats[t] * (1.0f / NN);
        float ex2 = stats[HD + t] * (1.0f / NN);
        float a   = ga[t];
        float var = ex2 - 2.0f * a * m * m + a * a * m * m;
        float sc  = gw[t] * rsqrtf(var + GEPS);
        csc[t]      = sc;
        csc[HD + t] = sc * (b1[t] - a * m) + gb[t];
    }
    __syncthreads();
    const int slot = blockIdx.x * 64 + (t & 63);
    const int quarter = t >> 6;
    float4 acc = make_float4(0.f, 0.f, 0.f, 0.f);
    if (slot < NN * 10) {
        int n = slot / 10, c4 = slot % 10;
        int j1 = rowstart[n + 1];
        int j = rowstart[n] + quarter;
        float4 sc = ((const float4*)csc)[c4];
        float4 sh = ((const float4*)csc)[10 + c4];
        if (j < j1) {
            int2 se = csr[j];
            while (true) {
                int jn = j + 4;
                int2 sen;
                if (jn < j1) sen = csr[jn];
                float cf = __int_as_float(se.y);
                float4 v = *(const float4*)&agg1[(size_t)se.x * HD + c4 * 4];
                v.x = fmaxf(fmaf(sc.x, v.x, sh.x), 0.f);
                v.y = fmaxf(fmaf(sc.y, v.y, sh.y), 0.f);
                v.z = fmaxf(fmaf(sc.z, v.z, sh.z), 0.f);
                v.w = fmaxf(fmaf(sc.w, v.w, sh.w), 0.f);
                acc.x = fmaf(v.x, cf, acc.x);
                acc.y = fmaf(v.y, cf, acc.y);
                acc.z = fmaf(v.z, cf, acc.z);
                acc.w = fmaf(v.w, cf, acc.w);
                if (jn >= j1) break;
                se = sen; j = jn;
            }
        }
    }
    part[t] = acc;
    __syncthreads();
    if (quarter == 0 && slot < NN * 10) {
        float4 p1 = part[t + 64], p2 = part[t + 128], p3 = part[t + 192];
        acc.x += p1.x + p2.x + p3.x;
        acc.y += p1.y + p2.y + p3.y;
        acc.z += p1.z + p2.z + p3.z;
        acc.w += p1.w + p2.w + p3.w;
        ((float4*)aggh)[slot] = acc;
    }
}

// ---------------- heads (all three in one dispatch; z selects head) ----------------
__device__ __forceinline__ float activate_rt(float z, int act) {
    if (act == 0) {                    // mean: clip(exp, 1e-5, 1e6)
        return fminf(fmaxf(__expf(z), 1e-5f), 1e6f);
    } else if (act == 1) {             // disp: clip(softplus, 1e-4, 1e4)
        float sp = fmaxf(z, 0.0f) + __logf(1.0f + __expf(-fabsf(z)));
        return fminf(fmaxf(sp, 1e-4f), 1e4f);
    }
    return __fdividef(1.0f, 1.0f + __expf(-z));   // pi: sigmoid
}

#define FMA4(A, s, W)            \
    A.x = fmaf(s, W.x, A.x);     \
    A.y = fmaf(s, W.y, A.y);     \
    A.z = fmaf(s, W.z, A.z);     \
    A.w = fmaf(s, W.w, A.w);

// grid (ceil(NN/64), 4, 3). Block: 64 rows x 128 cols. Thread: 8 rows x 4 cols.
// W double-buffered in registers (prefetch kc+1 while FMA-ing kc); A-tile LDS
// reads batched 8-wide at top of body; bias hoisted. unroll 1 (reg control —
// round 6: full unroll blew VGPR to 256 + spill).
__global__ __launch_bounds__(256) void k_heads3(const float* __restrict__ aggh,
                                                const float* __restrict__ Wm,
                                                const float* __restrict__ bm,
                                                const float* __restrict__ Wd,
                                                const float* __restrict__ bd,
                                                const float* __restrict__ Wp,
                                                const float* __restrict__ bp,
                                                float* __restrict__ out) {
    __shared__ float a_s[40 * 64];   // k-major, 4-slot rotated within 16-row groups, 10 KB
    const int z = blockIdx.z;
    const float* W    = (z == 0) ? Wm : (z == 1) ? Wd : Wp;
    const float* bias = (z == 0) ? bm : (z == 1) ? bd : bp;
    float* o = out + (size_t)z * NN * FIN;

    const int t = threadIdx.x;
    const int rowbase = blockIdx.x * 64;
    const int colbase4 = blockIdx.y * 32;   // float4 units

    const int cg = t & 31;
    const float4 bv = *(const float4*)&bias[(colbase4 + cg) * 4];   // hoisted

    // stage aggh tile [64 rows] transposed to k-major with rotation (<=3-way wr bank)
    const float4* A4 = (const float4*)aggh;
#pragma unroll
    for (int q = 0; q < 3; ++q) {
        int idx4 = t + 256 * q;                 // 640 float4s = 64 rows x 10
        if (idx4 < 640) {
            int row = idx4 / 10, c4 = idx4 % 10;
            int grow = min(rowbase + row, NN - 1);
            float4 v = A4[(size_t)grow * 10 + c4];
            int p = (row & ~15) + (((row & 15) + ((c4 & 3) << 2)) & 15);
            int k0 = c4 << 2;
            a_s[(k0 + 0) * 64 + p] = v.x;
            a_s[(k0 + 1) * 64 + p] = v.y;
            a_s[(k0 + 2) * 64 + p] = v.z;
            a_s[(k0 + 3) * 64 + p] = v.w;
        }
    }
    __syncthreads();

    const int rg = t >> 5;              // 8-row group (0..7)
    const int base16 = (rg >> 1) * 4;
    const int half2 = (rg & 1) * 2;
    const float4* a_s4 = (const float4*)a_s;
    const float4* wp = (const float4*)W + colbase4 + cg;   // stride 128 float4 per k

    float4 wnx[4];
#pragma unroll
    for (int kk = 0; kk < 4; ++kk) wnx[kk] = wp[(size_t)kk * 128];

    float4 acc[8];
#pragma unroll
    for (int r = 0; r < 8; ++r) acc[r] = make_float4(0.f, 0.f, 0.f, 0.f);

#pragma unroll 1
    for (int kc = 0; kc < 10; ++kc) {
        const int rot = kc & 3;
        const int s0 = (half2 + rot) & 3;
        const int s1 = (half2 + 1 + rot) & 3;
        // batch A-tile reads for this kc
        float4 a0[4], a1[4];
#pragma unroll
        for (int kk = 0; kk < 4; ++kk) {
            const int k = (kc << 2) + kk;
            a0[kk] = a_s4[(k << 4) + base16 + s0];
            a1[kk] = a_s4[(k << 4) + base16 + s1];
        }
        // consume current W, prefetch next kc's W
        float4 wcur[4];
#pragma unroll
        for (int kk = 0; kk < 4; ++kk) wcur[kk] = wnx[kk];
        if (kc < 9) {
#pragma unroll
            for (int kk = 0; kk < 4; ++kk)
                wnx[kk] = wp[(size_t)(((kc + 1) << 2) + kk) * 128];
        }
#pragma unroll
        for (int kk = 0; kk < 4; ++kk) {
            float4 wv = wcur[kk];
            FMA4(acc[0], a0[kk].x, wv)
            FMA4(acc[1], a0[kk].y, wv)
            FMA4(acc[2], a0[kk].z, wv)
            FMA4(acc[3], a0[kk].w, wv)
            FMA4(acc[4], a1[kk].x, wv)
            FMA4(acc[5], a1[kk].y, wv)
            FMA4(acc[6], a1[kk].z, wv)
            FMA4(acc[7], a1[kk].w, wv)
        }
    }

    float4* out4 = (float4*)o;
#pragma unroll
    for (int rr = 0; rr < 8; ++rr) {
        int grow = rowbase + (rg << 3) + rr;
        if (grow < NN) {
            float4 a = acc[rr];
            float4 ov;
            ov.x = activate_rt(a.x + bv.x, z);
            ov.y = activate_rt(a.y + bv.y, z);
            ov.z = activate_rt(a.z + bv.z, z);
            ov.w = activate_rt(a.w + bv.w, z);
            out4[(size_t)grow * 128 + colbase4 + cg] = ov;
        }
    }
}

extern "C" void kernel_launch(void* const* d_in, const int* in_sizes, int n_in,
                              void* d_out, int out_size, void* d_ws, size_t ws_size,
                              hipStream_t stream) {
    const float* x   = (const float*)d_in[0];
    const int*   src = (const int*)d_in[1];
    const int*   dst = (const int*)d_in[2];
    const float* W1  = (const float*)d_in[3];
    const float* b1  = (const float*)d_in[4];
    const float* gnw = (const float*)d_in[5];
    const float* gnb = (const float*)d_in[6];
    const float* gna = (const float*)d_in[7];
    const float* Wm  = (const float*)d_in[8];
    const float* bm  = (const float*)d_in[9];
    const float* Wd  = (const float*)d_in[10];
    const float* bd  = (const float*)d_in[11];
    const float* Wp  = (const float*)d_in[12];
    const float* bp  = (const float*)d_in[13];
    const int E = in_sizes[1];

    // workspace layout: zero-region (cnt,cur,stats) is 16B-aligned by construction
    float* ws       = (float*)d_ws;
    float* h1       = ws;                          // NN*HD  (mm1 out; later aggh)
    float* agg1     = h1 + (size_t)NN * HD;        // NN*HD  (gather1 out)
    int*   cnt      = (int*)(agg1 + (size_t)NN * HD);  // NN   } zeroed (int4)
    int*   cur      = cnt + NN;                    // NN     } zeroed
    float* stats    = (float*)(cur + NN);          // 2*HD   } zeroed
    float* dis      = stats + 2 * HD;              // NN
    int*   rowstart = (int*)(dis + NN);            // NN+1 (+1 pad for int2 align)
    int2*  csr      = (int2*)(rowstart + NN + 2);  // E int2, 8B-aligned
    float* out      = (float*)d_out;

    // mm1 + zero fused (zero blocks ride along; cnt zeroed before k_hist runs)
    k_mm1z<<<MM1_BLOCKS + ZERO_BLOCKS, 256, 0, stream>>>(x, W1, h1, (int4*)cnt);
    k_hist<<<(E + 255) / 256, 256, 0, stream>>>(dst, cnt, E);
    k_scan<<<1, 1024, 0, stream>>>(cnt, rowstart, dis);
    k_fill<<<(E + 255) / 256, 256, 0, stream>>>(src, dst, rowstart, cur, dis, csr, E);
    const int gblocks = (NN * 10 + 63) / 64;
    k_gather1<<<gblocks, 256, 0, stream>>>(rowstart, csr, h1, b1, agg1, stats);
    k_gather2<<<gblocks, 256, 0, stream>>>(rowstart, csr, agg1, stats,
                                           b1, gnw, gnb, gna, h1);
    dim3 hgrid((NN + 63) / 64, 4, 3);
    k_heads3<<<hgrid, 256, 0, stream>>>(h1, Wm, bm, Wd, bd, Wp, bp, out);
}

// Round 10
// 126.105 us; speedup vs baseline: 1.2977x; 1.2977x over previous
//
#include <hip/hip_runtime.h>
#include <math.h>

#define NN 10000
#define FIN 512
#define HD 40
#define GEPS 1e-5f

#define ZI4 ((2 * NN + 2 * HD) / 4)       // 5020 int4s (cnt, cur, stats)
#define MM1_BLOCKS ((NN + 15) / 16)       // 625
#define ZERO_BLOCKS ((ZI4 + 255) / 256)   // 20

// ---------------- CSR build ----------------
__global__ void k_hist(const int* __restrict__ dst, int* __restrict__ cnt, int E) {
    int e = blockIdx.x * blockDim.x + threadIdx.x;
    if (e < E) atomicAdd(&cnt[dst[e]], 1);
}

// single block, 1024 threads; 10 rows per thread; fused dis=rsqrt(deg)
__global__ __launch_bounds__(1024) void k_scan(const int* __restrict__ cnt,
                                               int* __restrict__ rowstart,
                                               float* __restrict__ dis) {
    __shared__ int lds[1024];
    const int t = threadIdx.x;
    const int start = t * 10;
    const int end = min(start + 10, NN);
    int s = 0;
    for (int i = start; i < end; ++i) s += cnt[i];
    lds[t] = s;
    __syncthreads();
    for (int off = 1; off < 1024; off <<= 1) {
        int v = (t >= off) ? lds[t - off] : 0;
        __syncthreads();
        lds[t] += v;
        __syncthreads();
    }
    int run = lds[t] - s;   // exclusive prefix
    for (int i = start; i < end; ++i) {
        int c = cnt[i];
        rowstart[i] = run;
        run += c;
        dis[i] = rsqrtf((float)c);
    }
    if (end == NN) rowstart[NN] = run;
}

__global__ void k_fill(const int* __restrict__ src, const int* __restrict__ dst,
                       const int* __restrict__ rowstart, int* __restrict__ cur,
                       const float* __restrict__ dis, int2* __restrict__ csr, int E) {
    int e = blockIdx.x * blockDim.x + threadIdx.x;
    if (e >= E) return;
    int s = src[e], d = dst[e];
    int pos = rowstart[d] + atomicAdd(&cur[d], 1);
    int2 v;
    v.x = s;
    v.y = __float_as_int(dis[s] * dis[d]);
    csr[pos] = v;
}

// ---------------- h1 = x @ W1 (16 rows x 16 kgroups; spare blocks zero cnt/cur/stats) ----------------
__global__ __launch_bounds__(256) void k_mm1z(const float* __restrict__ x,
                                              const float* __restrict__ W1,
                                              float* __restrict__ h1,
                                              int4* __restrict__ zbuf) {
    if (blockIdx.x >= MM1_BLOCKS) {       // zero-duty blocks
        int i = (blockIdx.x - MM1_BLOCKS) * 256 + threadIdx.x;
        if (i < ZI4) zbuf[i] = make_int4(0, 0, 0, 0);
        return;
    }
    __shared__ float red[256 * 41];       // 41-pad: odd stride -> conflict-free
    const int tid = threadIdx.x;
    const int r = tid & 15;
    const int kg = tid >> 4;              // 0..15, 32 k each
    const int row = blockIdx.x * 16 + r;
    const int rowc = min(row, NN - 1);
    const float4* xr = (const float4*)(x + (size_t)rowc * FIN + kg * 32);
    float acc[HD];
#pragma unroll
    for (int c = 0; c < HD; ++c) acc[c] = 0.f;
#pragma unroll 2
    for (int q = 0; q < 8; ++q) {
        float4 xv = xr[q];
        const float* wbase = W1 + (size_t)(kg * 32 + q * 4) * HD;
#pragma unroll
        for (int kk = 0; kk < 4; ++kk) {
            float xs = (kk == 0) ? xv.x : (kk == 1) ? xv.y : (kk == 2) ? xv.z : xv.w;
#pragma unroll
            for (int c4 = 0; c4 < 10; ++c4) {
                float4 wv = *(const float4*)(wbase + kk * HD + c4 * 4);
                acc[c4 * 4 + 0] = fmaf(xs, wv.x, acc[c4 * 4 + 0]);
                acc[c4 * 4 + 1] = fmaf(xs, wv.y, acc[c4 * 4 + 1]);
                acc[c4 * 4 + 2] = fmaf(xs, wv.z, acc[c4 * 4 + 2]);
                acc[c4 * 4 + 3] = fmaf(xs, wv.w, acc[c4 * 4 + 3]);
            }
        }
    }
#pragma unroll
    for (int c = 0; c < HD; ++c) red[tid * 41 + c] = acc[c];
    __syncthreads();
    if (tid < 160) {                      // 16 rows x 10 float4
        int rr = tid / 10, c4 = tid % 10;
        float o0 = 0.f, o1 = 0.f, o2 = 0.f, o3 = 0.f;
#pragma unroll
        for (int kg2 = 0; kg2 < 16; ++kg2) {
            const float* p = &red[(kg2 * 16 + rr) * 41 + c4 * 4];
            o0 += p[0]; o1 += p[1]; o2 += p[2]; o3 += p[3];
        }
        int orow = blockIdx.x * 16 + rr;
        if (orow < NN)
            *(float4*)&h1[(size_t)orow * HD + c4 * 4] = make_float4(o0, o1, o2, o3);
    }
}

// ---------------- gather: out[n] = sum coef * f(hin[src]) ----------------
// 2 threads per (node,c4) slot, each a CONTIGUOUS half of the edge range,
// 4 independent edges in flight per round (clamp+mask tail keeps MLP shape).
template <bool NORM>
__global__ __launch_bounds__(256) void k_gather(const int* __restrict__ rowstart,
                                                const int2* __restrict__ csr,
                                                const float* __restrict__ hin,
                                                const float* __restrict__ stats,
                                                const float* __restrict__ b1,
                                                const float* __restrict__ gw,
                                                const float* __restrict__ gb,
                                                const float* __restrict__ ga,
                                                float* __restrict__ aggout) {
    __shared__ float4 part[256];
    __shared__ float csc[2 * HD];
    const int t = threadIdx.x;
    if (NORM) {
        if (t < HD) {
            float m   = stats[t] * (1.0f / NN);
            float ex2 = stats[HD + t] * (1.0f / NN);
            float a   = ga[t];
            float var = ex2 - 2.0f * a * m * m + a * a * m * m;
            float sc  = gw[t] * rsqrtf(var + GEPS);
            csc[t]      = sc;
            csc[HD + t] = sc * (b1[t] - a * m) + gb[t];
        }
        __syncthreads();
    }
    const int slot = blockIdx.x * 128 + (t & 127);
    const int half = t >> 7;
    float4 acc = make_float4(0.f, 0.f, 0.f, 0.f);
    if (slot < NN * 10) {
        const int n = slot / 10, c4 = slot % 10;
        const int j0 = rowstart[n], j1 = rowstart[n + 1];
        const int mid = j0 + ((j1 - j0 + 1) >> 1);
        const int ja = half ? mid : j0;
        const int jb = half ? j1 : mid;
        float4 sc, sh;
        if (NORM) {
            sc = ((const float4*)csc)[c4];
            sh = ((const float4*)csc)[10 + c4];
        }
        for (int j = ja; j < jb; j += 4) {
            const int jm = jb - 1;
            int2 e0 = csr[j];
            int2 e1 = csr[min(j + 1, jm)];
            int2 e2 = csr[min(j + 2, jm)];
            int2 e3 = csr[min(j + 3, jm)];
            float4 v0 = *(const float4*)&hin[(size_t)e0.x * HD + c4 * 4];
            float4 v1 = *(const float4*)&hin[(size_t)e1.x * HD + c4 * 4];
            float4 v2 = *(const float4*)&hin[(size_t)e2.x * HD + c4 * 4];
            float4 v3 = *(const float4*)&hin[(size_t)e3.x * HD + c4 * 4];
            float c0 = __int_as_float(e0.y);
            float c1 = (j + 1 < jb) ? __int_as_float(e1.y) : 0.f;
            float c2 = (j + 2 < jb) ? __int_as_float(e2.y) : 0.f;
            float c3 = (j + 3 < jb) ? __int_as_float(e3.y) : 0.f;
            if (NORM) {
                v0.x = fmaxf(fmaf(sc.x, v0.x, sh.x), 0.f);
                v0.y = fmaxf(fmaf(sc.y, v0.y, sh.y), 0.f);
                v0.z = fmaxf(fmaf(sc.z, v0.z, sh.z), 0.f);
                v0.w = fmaxf(fmaf(sc.w, v0.w, sh.w), 0.f);
                v1.x = fmaxf(fmaf(sc.x, v1.x, sh.x), 0.f);
                v1.y = fmaxf(fmaf(sc.y, v1.y, sh.y), 0.f);
                v1.z = fmaxf(fmaf(sc.z, v1.z, sh.z), 0.f);
                v1.w = fmaxf(fmaf(sc.w, v1.w, sh.w), 0.f);
                v2.x = fmaxf(fmaf(sc.x, v2.x, sh.x), 0.f);
                v2.y = fmaxf(fmaf(sc.y, v2.y, sh.y), 0.f);
                v2.z = fmaxf(fmaf(sc.z, v2.z, sh.z), 0.f);
                v2.w = fmaxf(fmaf(sc.w, v2.w, sh.w), 0.f);
                v3.x = fmaxf(fmaf(sc.x, v3.x, sh.x), 0.f);
                v3.y = fmaxf(fmaf(sc.y, v3.y, sh.y), 0.f);
                v3.z = fmaxf(fmaf(sc.z, v3.z, sh.z), 0.f);
                v3.w = fmaxf(fmaf(sc.w, v3.w, sh.w), 0.f);
            }
            acc.x = fmaf(v0.x, c0, fmaf(v1.x, c1, fmaf(v2.x, c2, fmaf(v3.x, c3, acc.x))));
            acc.y = fmaf(v0.y, c0, fmaf(v1.y, c1, fmaf(v2.y, c2, fmaf(v3.y, c3, acc.y))));
            acc.z = fmaf(v0.z, c0, fmaf(v1.z, c1, fmaf(v2.z, c2, fmaf(v3.z, c3, acc.z))));
            acc.w = fmaf(v0.w, c0, fmaf(v1.w, c1, fmaf(v2.w, c2, fmaf(v3.w, c3, acc.w))));
        }
    }
    part[t] = acc;
    __syncthreads();
    if (half == 0 && slot < NN * 10) {
        float4 p2 = part[t + 128];
        acc.x += p2.x; acc.y += p2.y; acc.z += p2.z; acc.w += p2.w;
        ((float4*)aggout)[slot] = acc;
    }
}

// ---------------- GraphNorm stats over agg1 (80 blocks, c4-constant stride) ----------------
__global__ __launch_bounds__(256) void k_stats(const float* __restrict__ agg1,
                                               const float* __restrict__ b1,
                                               float* __restrict__ stats) {
    __shared__ float s0[HD], s1[HD];
    if (threadIdx.x < HD) { s0[threadIdx.x] = 0.f; s1[threadIdx.x] = 0.f; }
    __syncthreads();
    const int gid = blockIdx.x * 256 + threadIdx.x;
    const int c4 = gid % 10;          // stride 20480 % 10 == 0 -> constant per thread
    float4 bv = ((const float4*)b1)[c4];
    float4 a0 = make_float4(0.f, 0.f, 0.f, 0.f);
    float4 a1 = a0;
    for (int i4 = gid; i4 < NN * 10; i4 += 80 * 256) {
        float4 v = ((const float4*)agg1)[i4];
        v.x += bv.x; v.y += bv.y; v.z += bv.z; v.w += bv.w;
        a0.x += v.x; a0.y += v.y; a0.z += v.z; a0.w += v.w;
        a1.x = fmaf(v.x, v.x, a1.x);
        a1.y = fmaf(v.y, v.y, a1.y);
        a1.z = fmaf(v.z, v.z, a1.z);
        a1.w = fmaf(v.w, v.w, a1.w);
    }
    atomicAdd(&s0[c4 * 4 + 0], a0.x); atomicAdd(&s0[c4 * 4 + 1], a0.y);
    atomicAdd(&s0[c4 * 4 + 2], a0.z); atomicAdd(&s0[c4 * 4 + 3], a0.w);
    atomicAdd(&s1[c4 * 4 + 0], a1.x); atomicAdd(&s1[c4 * 4 + 1], a1.y);
    atomicAdd(&s1[c4 * 4 + 2], a1.z); atomicAdd(&s1[c4 * 4 + 3], a1.w);
    __syncthreads();
    if (threadIdx.x < HD) {
        atomicAdd(&stats[threadIdx.x], s0[threadIdx.x]);
        atomicAdd(&stats[HD + threadIdx.x], s1[threadIdx.x]);
    }
}

// ---------------- heads (all three in one dispatch; z selects head) ----------------
__device__ __forceinline__ float activate_rt(float z, int act) {
    if (act == 0) {                    // mean: clip(exp, 1e-5, 1e6)
        return fminf(fmaxf(__expf(z), 1e-5f), 1e6f);
    } else if (act == 1) {             // disp: clip(softplus, 1e-4, 1e4)
        float sp = fmaxf(z, 0.0f) + __logf(1.0f + __expf(-fabsf(z)));
        return fminf(fmaxf(sp, 1e-4f), 1e4f);
    }
    return __fdividef(1.0f, 1.0f + __expf(-z));   // pi: sigmoid
}

#define FMA4(A, s, W)            \
    A.x = fmaf(s, W.x, A.x);     \
    A.y = fmaf(s, W.y, A.y);     \
    A.z = fmaf(s, W.z, A.z);     \
    A.w = fmaf(s, W.w, A.w);

// grid (ceil(NN/64), 4, 3). Block: 64 rows x 128 cols. Thread: 8 rows x 4 cols.
// W double-buffered in registers; A-tile LDS batched; unroll 1 (reg control).
__global__ __launch_bounds__(256) void k_heads3(const float* __restrict__ aggh,
                                                const float* __restrict__ Wm,
                                                const float* __restrict__ bm,
                                                const float* __restrict__ Wd,
                                                const float* __restrict__ bd,
                                                const float* __restrict__ Wp,
                                                const float* __restrict__ bp,
                                                float* __restrict__ out) {
    __shared__ float a_s[40 * 64];   // k-major, 4-slot rotated within 16-row groups, 10 KB
    const int z = blockIdx.z;
    const float* W    = (z == 0) ? Wm : (z == 1) ? Wd : Wp;
    const float* bias = (z == 0) ? bm : (z == 1) ? bd : bp;
    float* o = out + (size_t)z * NN * FIN;

    const int t = threadIdx.x;
    const int rowbase = blockIdx.x * 64;
    const int colbase4 = blockIdx.y * 32;   // float4 units

    const int cg = t & 31;
    const float4 bv = *(const float4*)&bias[(colbase4 + cg) * 4];   // hoisted

    // stage aggh tile [64 rows] transposed to k-major with rotation (<=3-way wr bank)
    const float4* A4 = (const float4*)aggh;
#pragma unroll
    for (int q = 0; q < 3; ++q) {
        int idx4 = t + 256 * q;                 // 640 float4s = 64 rows x 10
        if (idx4 < 640) {
            int row = idx4 / 10, c4 = idx4 % 10;
            int grow = min(rowbase + row, NN - 1);
            float4 v = A4[(size_t)grow * 10 + c4];
            int p = (row & ~15) + (((row & 15) + ((c4 & 3) << 2)) & 15);
            int k0 = c4 << 2;
            a_s[(k0 + 0) * 64 + p] = v.x;
            a_s[(k0 + 1) * 64 + p] = v.y;
            a_s[(k0 + 2) * 64 + p] = v.z;
            a_s[(k0 + 3) * 64 + p] = v.w;
        }
    }
    __syncthreads();

    const int rg = t >> 5;              // 8-row group (0..7)
    const int base16 = (rg >> 1) * 4;
    const int half2 = (rg & 1) * 2;
    const float4* a_s4 = (const float4*)a_s;
    const float4* wp = (const float4*)W + colbase4 + cg;   // stride 128 float4 per k

    float4 wnx[4];
#pragma unroll
    for (int kk = 0; kk < 4; ++kk) wnx[kk] = wp[(size_t)kk * 128];

    float4 acc[8];
#pragma unroll
    for (int r = 0; r < 8; ++r) acc[r] = make_float4(0.f, 0.f, 0.f, 0.f);

#pragma unroll 1
    for (int kc = 0; kc < 10; ++kc) {
        const int rot = kc & 3;
        const int s0 = (half2 + rot) & 3;
        const int s1 = (half2 + 1 + rot) & 3;
        float4 a0[4], a1[4];
#pragma unroll
        for (int kk = 0; kk < 4; ++kk) {
            const int k = (kc << 2) + kk;
            a0[kk] = a_s4[(k << 4) + base16 + s0];
            a1[kk] = a_s4[(k << 4) + base16 + s1];
        }
        float4 wcur[4];
#pragma unroll
        for (int kk = 0; kk < 4; ++kk) wcur[kk] = wnx[kk];
        if (kc < 9) {
#pragma unroll
            for (int kk = 0; kk < 4; ++kk)
                wnx[kk] = wp[(size_t)(((kc + 1) << 2) + kk) * 128];
        }
#pragma unroll
        for (int kk = 0; kk < 4; ++kk) {
            float4 wv = wcur[kk];
            FMA4(acc[0], a0[kk].x, wv)
            FMA4(acc[1], a0[kk].y, wv)
            FMA4(acc[2], a0[kk].z, wv)
            FMA4(acc[3], a0[kk].w, wv)
            FMA4(acc[4], a1[kk].x, wv)
            FMA4(acc[5], a1[kk].y, wv)
            FMA4(acc[6], a1[kk].z, wv)
            FMA4(acc[7], a1[kk].w, wv)
        }
    }

    float4* out4 = (float4*)o;
#pragma unroll
    for (int rr = 0; rr < 8; ++rr) {
        int grow = rowbase + (rg << 3) + rr;
        if (grow < NN) {
            float4 a = acc[rr];
            float4 ov;
            ov.x = activate_rt(a.x + bv.x, z);
            ov.y = activate_rt(a.y + bv.y, z);
            ov.z = activate_rt(a.z + bv.z, z);
            ov.w = activate_rt(a.w + bv.w, z);
            out4[(size_t)grow * 128 + colbase4 + cg] = ov;
        }
    }
}

extern "C" void kernel_launch(void* const* d_in, const int* in_sizes, int n_in,
                              void* d_out, int out_size, void* d_ws, size_t ws_size,
                              hipStream_t stream) {
    const float* x   = (const float*)d_in[0];
    const int*   src = (const int*)d_in[1];
    const int*   dst = (const int*)d_in[2];
    const float* W1  = (const float*)d_in[3];
    const float* b1  = (const float*)d_in[4];
    const float* gnw = (const float*)d_in[5];
    const float* gnb = (const float*)d_in[6];
    const float* gna = (const float*)d_in[7];
    const float* Wm  = (const float*)d_in[8];
    const float* bm  = (const float*)d_in[9];
    const float* Wd  = (const float*)d_in[10];
    const float* bd  = (const float*)d_in[11];
    const float* Wp  = (const float*)d_in[12];
    const float* bp  = (const float*)d_in[13];
    const int E = in_sizes[1];

    // workspace layout: zero-region (cnt,cur,stats) is 16B-aligned by construction
    float* ws       = (float*)d_ws;
    float* h1       = ws;                          // NN*HD  (mm1 out; later aggh)
    float* agg1     = h1 + (size_t)NN * HD;        // NN*HD  (gather1 out)
    int*   cnt      = (int*)(agg1 + (size_t)NN * HD);  // NN   } zeroed (int4)
    int*   cur      = cnt + NN;                    // NN     } zeroed
    float* stats    = (float*)(cur + NN);          // 2*HD   } zeroed
    float* dis      = stats + 2 * HD;              // NN
    int*   rowstart = (int*)(dis + NN);            // NN+1 (+1 pad for int2 align)
    int2*  csr      = (int2*)(rowstart + NN + 2);  // E int2, 8B-aligned
    float* out      = (float*)d_out;

    // mm1 + zero fused (zero blocks ride along; cnt zeroed before k_hist runs)
    k_mm1z<<<MM1_BLOCKS + ZERO_BLOCKS, 256, 0, stream>>>(x, W1, h1, (int4*)cnt);
    k_hist<<<(E + 255) / 256, 256, 0, stream>>>(dst, cnt, E);
    k_scan<<<1, 1024, 0, stream>>>(cnt, rowstart, dis);
    k_fill<<<(E + 255) / 256, 256, 0, stream>>>(src, dst, rowstart, cur, dis, csr, E);
    const int gblocks = (NN * 10 + 127) / 128;
    k_gather<false><<<gblocks, 256, 0, stream>>>(rowstart, csr, h1, nullptr,
                                                 nullptr, nullptr, nullptr, nullptr, agg1);
    k_stats<<<80, 256, 0, stream>>>(agg1, b1, stats);
    k_gather<true><<<gblocks, 256, 0, stream>>>(rowstart, csr, agg1, stats,
                                                b1, gnw, gnb, gna, h1);
    dim3 hgrid((NN + 63) / 64, 4, 3);
    k_heads3<<<hgrid, 256, 0, stream>>>(h1, Wm, bm, Wd, bd, Wp, bp, out);
}